// Round 7
// baseline (219.520 us; speedup 1.0000x reference)
//
#include <hip/hip_runtime.h>

#define THREADS 1024
#define BINS 4096
#define CAP 4096
#define FLOOR_KEY 0xC0200000u   /* f2k(2.5f): candidates are logits >= 2.5 */
#define MARGIN 8u               /* ulp margin so no sub-floor element can tie after /t */

__device__ __forceinline__ unsigned rotl32(unsigned x, unsigned r) {
  return (x << r) | (x >> (32u - r));
}

// Threefry-2x32, 20 rounds, key=(0,42); returns x0^x1 (jax_threefry_partitionable
// 32-bit random_bits; counts=(hi=0, lo=flat) since n < 2^32).
__device__ __forceinline__ unsigned threefry_xor_0_42(unsigned x0, unsigned x1) {
  const unsigned k0 = 0u, k1 = 42u, k2 = 0u ^ 42u ^ 0x1BD11BDAu;
  x0 += k0; x1 += k1;
#define TF_R(r) { x0 += x1; x1 = rotl32(x1, r); x1 ^= x0; }
  TF_R(13) TF_R(15) TF_R(26) TF_R(6)
  x0 += k1; x1 += k2 + 1u;
  TF_R(17) TF_R(29) TF_R(16) TF_R(24)
  x0 += k2; x1 += k0 + 2u;
  TF_R(13) TF_R(15) TF_R(26) TF_R(6)
  x0 += k0; x1 += k1 + 3u;
  TF_R(17) TF_R(29) TF_R(16) TF_R(24)
  x0 += k1; x1 += k2 + 4u;
  TF_R(13) TF_R(15) TF_R(26) TF_R(6)
  x0 += k2; x1 += k0 + 5u;
#undef TF_R
  return x0 ^ x1;
}

// Bit-exact jax.random.gumbel(key(42))[flat] under partitionable threefry.
__device__ __forceinline__ float gumbel_at(unsigned flat) {
  unsigned bits = threefry_xor_0_42(0u, flat);
  float fl = __uint_as_float((bits >> 9) | 0x3F800000u) - 1.0f;  // [0,1)
  const float tiny = 1.17549435e-38f;
  float u = fmaxf(fl + tiny, tiny);   // == JAX's max(tiny, fl*(1-tiny)+tiny) bitwise
  return -logf(-logf(u));
}

// Monotone float <-> uint key (order-preserving, bijective).
__device__ __forceinline__ unsigned f2k(float f) {
  unsigned b = __float_as_uint(f);
  return (b & 0x80000000u) ? ~b : (b ^ 0x80000000u);
}
__device__ __forceinline__ float k2f(unsigned k) {
  unsigned b = (k & 0x80000000u) ? (k ^ 0x80000000u) : ~k;
  return __uint_as_float(b);
}

__global__ __launch_bounds__(THREADS) void sampler_kernel(
    const float* __restrict__ logits, const float* __restrict__ temps,
    const int* __restrict__ topk_ptr, int* __restrict__ out, int V) {
  const int row = blockIdx.x;
  const int tid = threadIdx.x;
  const unsigned K = (unsigned)(*topk_ptr);

  const float* rowp = logits + (size_t)row * (size_t)V;
  const float4* rowp4 = (const float4*)rowp;
  const int nv4 = V >> 2;
  const int half4 = nv4 >> 1;

  __shared__ unsigned hist[BINS];          // 16 KB (fallback only)
  __shared__ unsigned cand_key[CAP];       // 16 KB
  __shared__ unsigned cand_idx[CAP];       // 16 KB
  __shared__ float    rv[THREADS];         // 4 KB
  __shared__ unsigned ri[THREADS];         // 4 KB
  __shared__ unsigned ncand, sBstar, sAbove, sK50;

  if (tid == 0) { ncand = 0u; sBstar = 0u; sAbove = 0u; sK50 = 0u; }
  __syncthreads();

  // ---- Fast pass: one HBM stream; append all elements with key >= FLOOR_KEY ----
  for (int i = tid; i < half4; i += THREADS) {
    float4 a = rowp4[i];
    float4 b = rowp4[i + half4];
    float f[8] = {a.x, a.y, a.z, a.w, b.x, b.y, b.z, b.w};
#pragma unroll
    for (int e = 0; e < 8; ++e) {
      unsigned key = f2k(f[e]);
      if (key >= FLOOR_KEY) {
        unsigned col = (unsigned)((e < 4 ? i : i + half4) * 4 + (e & 3));
        unsigned p = atomicAdd(&ncand, 1u);
        if (p < CAP) { cand_key[p] = key; cand_idx[p] = col; }
      }
    }
  }
  // scalar tail (V % 8 != 0 elements; none for V=128000)
  for (int j = (half4 * 2) * 4 + tid; j < V; j += THREADS) {
    unsigned key = f2k(rowp[j]);
    if (key >= FLOOR_KEY) {
      unsigned p = atomicAdd(&ncand, 1u);
      if (p < CAP) { cand_key[p] = key; cand_idx[p] = (unsigned)j; }
    }
  }
  __syncthreads();

  const bool tryFast = (ncand >= K && ncand <= (unsigned)CAP);
  unsigned c = min(ncand, (unsigned)CAP);

  // ---- Fast selection: exact K-th largest among candidates (cntAbove = 0) ----
  if (tryFast) {
    for (unsigned i = tid; i < c; i += THREADS) {
      unsigned ki = cand_key[i];
      unsigned gt = 0, eq = 0;
      for (unsigned j = 0; j < c; ++j) {
        unsigned kj = cand_key[j];
        gt += (kj > ki) ? 1u : 0u;
        eq += (kj == ki) ? 1u : 0u;
      }
      if (gt < K && gt + eq >= K) sK50 = ki;   // unique tie-group; benign same-value writes
    }
  }
  __syncthreads();

  // Margin: every non-candidate is >=8 ulps below the K-th key, so it cannot
  // tie s50 after the fp32 division for any t. Otherwise: exact fallback.
  const bool fastOK = tryFast && (sK50 >= FLOOR_KEY + MARGIN);

  float bestV = -INFINITY;
  unsigned bestI = 0xFFFFFFFFu;
  const float t = temps[row];
  const unsigned rowBase = (unsigned)row * (unsigned)V;

  if (!fastOK) {
    // ================= Fallback: round-6 verified 3-phase algorithm =================
    for (int i = tid; i < BINS; i += THREADS) hist[i] = 0u;
    if (tid == 0) ncand = 0u;
    __syncthreads();

    for (int i = tid; i < nv4; i += THREADS) {
      float4 v = rowp4[i];
      atomicAdd(&hist[f2k(v.x) >> 20], 1u);
      atomicAdd(&hist[f2k(v.y) >> 20], 1u);
      atomicAdd(&hist[f2k(v.z) >> 20], 1u);
      atomicAdd(&hist[f2k(v.w) >> 20], 1u);
    }
    for (int j = nv4 * 4 + tid; j < V; j += THREADS) atomicAdd(&hist[f2k(rowp[j]) >> 20], 1u);
    __syncthreads();

    if (tid < 64) {
      const int lane = tid;
      unsigned s = 0;
      for (int k = 0; k < 64; ++k) s += hist[lane * 64 + k];
      unsigned suf = s;
#pragma unroll
      for (int off = 1; off < 64; off <<= 1) {
        unsigned o = __shfl_down(suf, off);
        if (lane + off < 64) suf += o;
      }
      unsigned sufn = __shfl_down(suf, 1);
      if (lane == 63) sufn = 0u;
      if (suf >= K && sufn < K) {
        unsigned run = sufn;
        for (int k = 63; k >= 0; --k) {
          unsigned h = hist[lane * 64 + k];
          unsigned nr = run + h;
          if (run < K && nr >= K) { sBstar = (unsigned)(lane * 64 + k); sAbove = run; }
          run = nr;
        }
      }
    }
    __syncthreads();

    const unsigned Bstar = sBstar;
    const unsigned cntAbove = sAbove;
    const unsigned long long binCeilP1 = ((unsigned long long)(Bstar + 1u)) << 20;
    const unsigned lowKey = (Bstar >= 1u) ? ((Bstar - 1u) << 20) : 0u;

    for (int i = tid; i < nv4; i += THREADS) {
      float4 v = rowp4[i];
      float f[4] = {v.x, v.y, v.z, v.w};
#pragma unroll
      for (int e = 0; e < 4; ++e) {
        unsigned key = f2k(f[e]);
        if (key < lowKey) continue;
        unsigned col = (unsigned)(i * 4 + e);
        if ((unsigned long long)key >= binCeilP1) {
          float sj = f[e] / t;
          float val = sj + gumbel_at(rowBase + col);
          if (val > bestV || (val == bestV && col < bestI)) { bestV = val; bestI = col; }
        } else {
          unsigned p = atomicAdd(&ncand, 1u);
          if (p < CAP) { cand_key[p] = key; cand_idx[p] = col; }
        }
      }
    }
    for (int j = nv4 * 4 + tid; j < V; j += THREADS) {
      unsigned key = f2k(rowp[j]);
      if (key < lowKey) continue;
      if ((unsigned long long)key >= binCeilP1) {
        float sj = rowp[j] / t;
        float val = sj + gumbel_at(rowBase + (unsigned)j);
        if (val > bestV || (val == bestV && (unsigned)j < bestI)) { bestV = val; bestI = (unsigned)j; }
      } else {
        unsigned p = atomicAdd(&ncand, 1u);
        if (p < CAP) { cand_key[p] = key; cand_idx[p] = (unsigned)j; }
      }
    }
    __syncthreads();

    c = min(ncand, (unsigned)CAP);
    for (unsigned i = tid; i < c; i += THREADS) {
      unsigned ki = cand_key[i];
      unsigned gt = 0, eq = 0;
      for (unsigned j = 0; j < c; ++j) {
        unsigned kj = cand_key[j];
        gt += (kj > ki) ? 1u : 0u;
        eq += (kj == ki) ? 1u : 0u;
      }
      if (cntAbove + gt < K && cntAbove + gt + eq >= K) sK50 = ki;
    }
    __syncthreads();
  }

  // ---- Common: exact division-mask + Gumbel-argmax over candidates ----
  const float s50 = k2f(sK50) / t;
  for (unsigned i = tid; i < c; i += THREADS) {
    unsigned col = cand_idx[i];
    if (col >= (unsigned)V) continue;
    float sj = k2f(cand_key[i]) / t;
    if (sj >= s50) {             // replicate `scaled < kth -> -inf` exactly
      float val = sj + gumbel_at(rowBase + col);
      if (val > bestV || (val == bestV && col < bestI)) { bestV = val; bestI = col; }
    }
  }

  // ---- Block argmax, first-index tie-break (matches jnp.argmax) ----
  rv[tid] = bestV; ri[tid] = bestI;
  __syncthreads();
  for (int off = THREADS / 2; off > 0; off >>= 1) {
    if (tid < off) {
      float v2 = rv[tid + off]; unsigned i2 = ri[tid + off];
      if (v2 > rv[tid] || (v2 == rv[tid] && i2 < ri[tid])) { rv[tid] = v2; ri[tid] = i2; }
    }
    __syncthreads();
  }
  if (tid == 0) out[row] = (int)((ri[0] < (unsigned)V) ? ri[0] : 0u);
}

extern "C" void kernel_launch(void* const* d_in, const int* in_sizes, int n_in,
                              void* d_out, int out_size, void* d_ws, size_t ws_size,
                              hipStream_t stream) {
  const float* logits = (const float*)d_in[0];
  const float* temps  = (const float*)d_in[1];
  const int*   topk   = (const int*)d_in[2];
  int* out = (int*)d_out;

  const int B = in_sizes[1];              // 256
  const int V = in_sizes[0] / B;          // 128000

  sampler_kernel<<<B, THREADS, 0, stream>>>(logits, temps, topk, out, V);
}